// Round 1
// baseline (10065.804 us; speedup 1.0000x reference)
//
#include <hip/hip_runtime.h>

typedef _Float16 f16;
typedef f16 f16x4 __attribute__((ext_vector_type(4)));
typedef f16 f16x8 __attribute__((ext_vector_type(8)));
typedef float f32x16 __attribute__((ext_vector_type(16)));

#define LDS_BYTES 156672
#define PART_OFF  122880
#define C_OFF     143360
#define Y1_ELEMS  33554432u

// ---------------------------------------------------------------------------
// x[b][t][k] (f32) -> slab[t][k/16][b][k%16] (f16)   (MFMA A-fragment layout)
// ---------------------------------------------------------------------------
__global__ void k_convert_x(const float* __restrict__ x, f16* __restrict__ slab) {
  __shared__ float tile[64][65];
  const int t = blockIdx.x;
  const int kc = blockIdx.y;
  {
    const int row = threadIdx.x >> 3, c8 = threadIdx.x & 7;
    const float* src = x + (((size_t)row << 9) + t) * 1024 + kc * 64 + c8 * 8;
    const float4 v0 = ((const float4*)src)[0];
    const float4 v1 = ((const float4*)src)[1];
    float* d = &tile[row][c8 * 8];
    d[0] = v0.x; d[1] = v0.y; d[2] = v0.z; d[3] = v0.w;
    d[4] = v1.x; d[5] = v1.y; d[6] = v1.z; d[7] = v1.w;
  }
  __syncthreads();
  {
    const int kbl = threadIdx.x >> 7;
    const int b = (threadIdx.x >> 1) & 63;
    const int half = threadIdx.x & 1;
    const float* s = &tile[b][kbl * 16 + half * 8];
    f16x8 o;
#pragma unroll
    for (int j = 0; j < 8; ++j) o[j] = (f16)s[j];
    f16* dst = slab + (size_t)t * 65536 + (size_t)(kc * 4 + kbl) * 1024 + b * 16 + half * 8;
    *(f16x8*)dst = o;
  }
}

// ---------------------------------------------------------------------------
// hidden[2][64][1024] f32 -> ring slot 1 of each layer (fragment layout); root=0
// ---------------------------------------------------------------------------
__global__ void k_init(const float* __restrict__ hidden, f16* __restrict__ h0r,
                       f16* __restrict__ h1r, unsigned* __restrict__ root) {
  const int idx = blockIdx.x * 256 + threadIdx.x;
  const int layer = idx >> 16, rem = idx & 65535, b = rem >> 10, k = rem & 1023;
  const float v = hidden[idx];
  f16* ring = layer ? h1r : h0r;
  ring[65536 + (k >> 4) * 1024 + b * 16 + (k & 15)] = (f16)v;
  if (idx == 0) *root = 0u;
}

// ---------------------------------------------------------------------------
// Persistent 2-layer GRU.
// 256 wgs: even-role = layer0 (8 h-cols each), odd-role = layer1 (8 h-cols).
// Weights (3 gates x [w_hh | w_ih], f16) resident in LDS.
// Per step: fused GEMM M=64,N=24,K=2048 split over 8 waves (src x mtile x khalf),
// LDS reduce, gate math, ring write, grid barrier (monotonic root counter).
// ---------------------------------------------------------------------------
__launch_bounds__(512, 1)
__global__ void k_gru(const float* __restrict__ w_ih0, const float* __restrict__ w_hh0,
                      const float* __restrict__ b_ih0, const float* __restrict__ b_hh0,
                      const float* __restrict__ w_ih1, const float* __restrict__ w_hh1,
                      const float* __restrict__ b_ih1, const float* __restrict__ b_hh1,
                      const float* __restrict__ hidden, const f16* __restrict__ xslab,
                      f16* __restrict__ h0ring, f16* __restrict__ h1ring,
                      unsigned* __restrict__ root, float* __restrict__ out) {
  __shared__ __align__(16) unsigned char smem[LDS_BYTES];
  const int tid = threadIdx.x;
  const int bid = blockIdx.x;
  const int role = (bid >> 3) & 1;                 // interleave roles across XCDs
  const int chunk = ((bid >> 4) << 3) | (bid & 7); // 0..127
  const int cbase = chunk * 8;

  const float* wsrc0 = role ? w_hh1 : w_hh0;  // recurrent half (k 0..1023)
  const float* wsrc1 = role ? w_ih1 : w_ih0;  // input half     (k 1024..2047)
  const float* bihp = role ? b_ih1 : b_ih0;
  const float* bhhp = role ? b_hh1 : b_hh0;

  const int lane = tid & 63, wid = tid >> 6;

  // ---- load weight slice into LDS: 48 rows (src x gate x col) of 1024 f32
  // LDS B layout: [kbg=src*64+k16][col_t=gate*8+c] : 32B of 16 f16, col stride 40B
#pragma unroll
  for (int j = 0; j < 6; ++j) {
    const int rid = wid * 6 + j;
    const int wsrc = rid / 24;
    const int rem = rid % 24;
    const int gate = rem >> 3, c = rem & 7;
    const float* wrow = (wsrc ? wsrc1 : wsrc0) + (size_t)(gate * 1024 + cbase + c) * 1024 + lane * 16;
    f16 v[16];
#pragma unroll
    for (int q = 0; q < 4; ++q) {
      const float4 f = ((const float4*)wrow)[q];
      v[q * 4 + 0] = (f16)f.x; v[q * 4 + 1] = (f16)f.y;
      v[q * 4 + 2] = (f16)f.z; v[q * 4 + 3] = (f16)f.w;
    }
    const int kbg = wsrc * 64 + lane;
    const int ct = gate * 8 + c;
    unsigned char* p = smem + kbg * 960 + ct * 40;
    const f16x4* vv = (const f16x4*)v;
    *(f16x4*)(p) = vv[0];
    *(f16x4*)(p + 8) = vv[1];
    *(f16x4*)(p + 16) = vv[2];
    *(f16x4*)(p + 24) = vv[3];
  }

  // ---- finish-phase per-thread constants: thread -> (batch fb, col fc)
  const int fb = tid >> 3, fc = tid & 7;
  const int cg = cbase + fc;
  const float bihr = bihp[cg], bihz = bihp[1024 + cg], bihn = bihp[2048 + cg];
  const float bhhr = bhhp[cg], bhhz = bhhp[1024 + cg], bhhn = bhhp[2048 + cg];
  float hprev = hidden[(size_t)role * 65536 + fb * 1024 + cg];

  // ---- MFMA wave roles
  const int src = wid & 1;          // 0: recurrent A, 1: input A
  const int mt = (wid >> 1) & 1;    // batch-row half (32 rows)
  const int kh = wid >> 2;          // K half within source (512)
  const int rowB = mt * 32 + (lane & 31);
  const int kg = lane >> 5;
  const int colf = lane & 31;
  const int colm = (colf < 24) ? colf : (colf - 8);
  const unsigned bofs_base = (unsigned)(src * 64 + kh * 32) * 960 + colm * 40 + kg * 16;
  float* Cpl = (float*)(smem + C_OFF);

  __syncthreads();

  unsigned step_target = 256u;
  for (int s = 0; s <= 512; ++s) {
    const bool active = role ? (s >= 1) : (s < 512);
    f32x16 acc;
#pragma unroll
    for (int e = 0; e < 16; ++e) acc[e] = 0.0f;

    if (active) {
      const f16* Abase;
      if (role == 0)
        Abase = src ? (xslab + (size_t)s * 65536) : (h0ring + (unsigned)((s - 1) & 1) * 65536);
      else
        Abase = src ? (h0ring + (unsigned)((s - 1) & 1) * 65536) : (h1ring + (unsigned)(s & 1) * 65536);
      const f16* ap = Abase + (kh * 32) * 1024 + rowB * 16 + kg * 8;
      unsigned bofs = bofs_base;
#pragma unroll 4
      for (int i = 0; i < 32; ++i) {
        const f16x8 a = *(const f16x8*)ap;
        const f16x4 blo = *(const f16x4*)(smem + bofs);
        const f16x4 bhi = *(const f16x4*)(smem + bofs + 8);
        const f16x8 bb = __builtin_shufflevector(blo, bhi, 0, 1, 2, 3, 4, 5, 6, 7);
        acc = __builtin_amdgcn_mfma_f32_32x32x16_f16(a, bb, acc, 0, 0, 0);
        ap += 1024;
        bofs += 960;
      }
      if (kh == 1) {
        float* pf = (float*)(smem + PART_OFF + (src * 2 + mt) * 5120 + lane * 80);
#pragma unroll
        for (int e = 0; e < 16; ++e) pf[e] = acc[e];
      }
    }
    __syncthreads();
    if (active && kh == 0) {
      const float* pf = (const float*)(smem + PART_OFF + (src * 2 + mt) * 5120 + lane * 80);
#pragma unroll
      for (int e = 0; e < 16; ++e) acc[e] += pf[e];
      if (colf < 24) {
#pragma unroll
        for (int r = 0; r < 16; ++r) {
          const int row = (r & 3) + 8 * (r >> 2) + 4 * kg + mt * 32;
          Cpl[src * 1664 + row * 26 + colf] = acc[r];
        }
      }
    }
    __syncthreads();
    if (active) {
      const float hr = Cpl[fb * 26 + fc],      xr = Cpl[1664 + fb * 26 + fc];
      const float hz = Cpl[fb * 26 + 8 + fc],  xz = Cpl[1664 + fb * 26 + 8 + fc];
      const float hn = Cpl[fb * 26 + 16 + fc], xn = Cpl[1664 + fb * 26 + 16 + fc];
      const float r = 1.0f / (1.0f + exp2f(-1.4426950408889634f * (xr + bihr + hr + bhhr)));
      const float z = 1.0f / (1.0f + exp2f(-1.4426950408889634f * (xz + bihz + hz + bhhz)));
      const float pn = (xn + bihn) + r * (hn + bhhn);
      const float u = exp2f(2.8853900817779268f * pn);
      const float n = 1.0f - 2.0f / (u + 1.0f);
      const float hnew = (1.0f - z) * n + z * hprev;
      hprev = hnew;
      f16* ring = role ? (h1ring + (unsigned)((s - 1) & 1) * 65536)
                       : (h0ring + (unsigned)(s & 1) * 65536);
      ring[(cg >> 4) * 1024 + fb * 16 + (cg & 15)] = (f16)hnew;
      if (role) {
        out[((size_t)fb * 512 + (s - 1)) * 1024 + cg] = hnew;
        if (s == 512) out[Y1_ELEMS + 65536u + fb * 1024u + cg] = hnew;
      } else {
        if (s == 511) out[Y1_ELEMS + fb * 1024u + cg] = hnew;
      }
    }
    __syncthreads();
    if (tid == 0) {
      __hip_atomic_fetch_add(root, 1u, __ATOMIC_RELEASE, __HIP_MEMORY_SCOPE_AGENT);
      while (__hip_atomic_load(root, __ATOMIC_RELAXED, __HIP_MEMORY_SCOPE_AGENT) < step_target) {
        __builtin_amdgcn_s_sleep(2);
      }
      __threadfence();  // acquire: invalidate L1/L2 before reading remote rings
    }
    step_target += 256u;
    __syncthreads();
  }
}

// ---------------------------------------------------------------------------
extern "C" void kernel_launch(void* const* d_in, const int* in_sizes, int n_in,
                              void* d_out, int out_size, void* d_ws, size_t ws_size,
                              hipStream_t stream) {
  (void)in_sizes; (void)n_in; (void)out_size; (void)ws_size;
  const float* x      = (const float*)d_in[0];
  const float* hidden = (const float*)d_in[1];
  const float* w_ih0  = (const float*)d_in[2];
  const float* w_hh0  = (const float*)d_in[3];
  const float* b_ih0  = (const float*)d_in[4];
  const float* b_hh0  = (const float*)d_in[5];
  const float* w_ih1  = (const float*)d_in[6];
  const float* w_hh1  = (const float*)d_in[7];
  const float* b_ih1  = (const float*)d_in[8];
  const float* b_hh1  = (const float*)d_in[9];
  float* out = (float*)d_out;

  unsigned char* ws = (unsigned char*)d_ws;
  f16* slab = (f16*)ws;                                   // 67,108,864 B
  f16* h0r = (f16*)(ws + 67108864u);                      //    262,144 B
  f16* h1r = (f16*)(ws + 67108864u + 262144u);            //    262,144 B
  unsigned* root = (unsigned*)(ws + 67108864u + 524288u); //        128 B

  hipLaunchKernelGGL(k_convert_x, dim3(512, 16), dim3(512), 0, stream, x, slab);
  hipLaunchKernelGGL(k_init, dim3(512), dim3(256), 0, stream, hidden, h0r, h1r, root);
  hipLaunchKernelGGL(k_gru, dim3(256), dim3(512), 0, stream,
                     w_ih0, w_hh0, b_ih0, b_hh0, w_ih1, w_hh1, b_ih1, b_hh1,
                     hidden, slab, h0r, h1r, root, out);
}

// Round 2
// 9663.438 us; speedup vs baseline: 1.0416x; 1.0416x over previous
//
#include <hip/hip_runtime.h>

typedef _Float16 f16;
typedef f16 f16x4 __attribute__((ext_vector_type(4)));
typedef f16 f16x8 __attribute__((ext_vector_type(8)));
typedef float f32x16 __attribute__((ext_vector_type(16)));

#define LDS_BYTES 156672
#define PART_OFF  122880
#define C_OFF     143360
#define Y1_ELEMS  33554432u

// ---------------------------------------------------------------------------
// x[b][t][k] (f32) -> slab[t][k/16][b][k%16] (f16)   (MFMA A-fragment layout)
// ---------------------------------------------------------------------------
__global__ void k_convert_x(const float* __restrict__ x, f16* __restrict__ slab) {
  __shared__ float tile[64][65];
  const int t = blockIdx.x;
  const int kc = blockIdx.y;
  {
    const int row = threadIdx.x >> 3, c8 = threadIdx.x & 7;
    const float* src = x + (((size_t)row << 9) + t) * 1024 + kc * 64 + c8 * 8;
    const float4 v0 = ((const float4*)src)[0];
    const float4 v1 = ((const float4*)src)[1];
    float* d = &tile[row][c8 * 8];
    d[0] = v0.x; d[1] = v0.y; d[2] = v0.z; d[3] = v0.w;
    d[4] = v1.x; d[5] = v1.y; d[6] = v1.z; d[7] = v1.w;
  }
  __syncthreads();
  {
    const int kbl = threadIdx.x >> 7;
    const int b = (threadIdx.x >> 1) & 63;
    const int half = threadIdx.x & 1;
    const float* s = &tile[b][kbl * 16 + half * 8];
    f16x8 o;
#pragma unroll
    for (int j = 0; j < 8; ++j) o[j] = (f16)s[j];
    f16* dst = slab + (size_t)t * 65536 + (size_t)(kc * 4 + kbl) * 1024 + b * 16 + half * 8;
    *(f16x8*)dst = o;
  }
}

// ---------------------------------------------------------------------------
// hidden[2][64][1024] f32 -> ring slot 1 of each layer (fragment layout); root=0
// ---------------------------------------------------------------------------
__global__ void k_init(const float* __restrict__ hidden, f16* __restrict__ h0r,
                       f16* __restrict__ h1r, unsigned* __restrict__ root) {
  const int idx = blockIdx.x * 256 + threadIdx.x;
  const int layer = idx >> 16, rem = idx & 65535, b = rem >> 10, k = rem & 1023;
  const float v = hidden[idx];
  f16* ring = layer ? h1r : h0r;
  ring[65536 + (k >> 4) * 1024 + b * 16 + (k & 15)] = (f16)v;
  if (idx == 0) *root = 0u;
}

// A-fragment loads: nontemporal (bypass L1/L2; rings are never cached anywhere,
// so no invalidates are needed for cross-XCD freshness) vs cached (x slab).
#define LD_NT(p) __builtin_nontemporal_load((const f16x8*)(p))
#define LD_CA(p) (*(const f16x8*)(p))

// 2-stage software-pipelined K-loop: batches of 8 f16x8 A-frags in flight.
#define GEMM_BODY(LD)                                                          \
  do {                                                                         \
    f16x8 ab0[8], ab1[8];                                                      \
    _Pragma("unroll") for (int j = 0; j < 8; ++j) ab0[j] = LD(ap + j * 1024);  \
    _Pragma("unroll") for (int j = 0; j < 8; ++j) ab1[j] = LD(ap + (8 + j) * 1024); \
    _Pragma("unroll") for (int j = 0; j < 8; ++j) {                            \
      const f16x4 blo = *(const f16x4*)(smem + bofs);                          \
      const f16x4 bhi = *(const f16x4*)(smem + bofs + 8);                      \
      const f16x8 bb = __builtin_shufflevector(blo, bhi, 0, 1, 2, 3, 4, 5, 6, 7); \
      acc = __builtin_amdgcn_mfma_f32_32x32x16_f16(ab0[j], bb, acc, 0, 0, 0);  \
      bofs += 960;                                                             \
      ab0[j] = LD(ap + (16 + j) * 1024);                                       \
    }                                                                          \
    _Pragma("unroll") for (int j = 0; j < 8; ++j) {                            \
      const f16x4 blo = *(const f16x4*)(smem + bofs);                          \
      const f16x4 bhi = *(const f16x4*)(smem + bofs + 8);                      \
      const f16x8 bb = __builtin_shufflevector(blo, bhi, 0, 1, 2, 3, 4, 5, 6, 7); \
      acc = __builtin_amdgcn_mfma_f32_32x32x16_f16(ab1[j], bb, acc, 0, 0, 0);  \
      bofs += 960;                                                             \
      ab1[j] = LD(ap + (24 + j) * 1024);                                       \
    }                                                                          \
    _Pragma("unroll") for (int j = 0; j < 8; ++j) {                            \
      const f16x4 blo = *(const f16x4*)(smem + bofs);                          \
      const f16x4 bhi = *(const f16x4*)(smem + bofs + 8);                      \
      const f16x8 bb = __builtin_shufflevector(blo, bhi, 0, 1, 2, 3, 4, 5, 6, 7); \
      acc = __builtin_amdgcn_mfma_f32_32x32x16_f16(ab0[j], bb, acc, 0, 0, 0);  \
      bofs += 960;                                                             \
    }                                                                          \
    _Pragma("unroll") for (int j = 0; j < 8; ++j) {                            \
      const f16x4 blo = *(const f16x4*)(smem + bofs);                          \
      const f16x4 bhi = *(const f16x4*)(smem + bofs + 8);                      \
      const f16x8 bb = __builtin_shufflevector(blo, bhi, 0, 1, 2, 3, 4, 5, 6, 7); \
      acc = __builtin_amdgcn_mfma_f32_32x32x16_f16(ab1[j], bb, acc, 0, 0, 0);  \
      bofs += 960;                                                             \
    }                                                                          \
  } while (0)

// ---------------------------------------------------------------------------
// Persistent 2-layer GRU. 256 wgs (128/layer, 8 h-cols each), weights in LDS.
// Rings move through the coherence point only (nt stores + nt loads): no
// threadfence / cache invalidates anywhere in the step loop.
// ---------------------------------------------------------------------------
__launch_bounds__(512, 1)
__global__ void k_gru(const float* __restrict__ w_ih0, const float* __restrict__ w_hh0,
                      const float* __restrict__ b_ih0, const float* __restrict__ b_hh0,
                      const float* __restrict__ w_ih1, const float* __restrict__ w_hh1,
                      const float* __restrict__ b_ih1, const float* __restrict__ b_hh1,
                      const float* __restrict__ hidden, const f16* __restrict__ xslab,
                      f16* __restrict__ h0ring, f16* __restrict__ h1ring,
                      unsigned* __restrict__ root, float* __restrict__ out) {
  __shared__ __align__(16) unsigned char smem[LDS_BYTES];
  const int tid = threadIdx.x;
  const int bid = blockIdx.x;
  const int role = (bid >> 3) & 1;                 // interleave roles across XCDs
  const int chunk = ((bid >> 4) << 3) | (bid & 7); // 0..127
  const int cbase = chunk * 8;

  const float* wsrc0 = role ? w_hh1 : w_hh0;  // recurrent half (k 0..1023)
  const float* wsrc1 = role ? w_ih1 : w_ih0;  // input half     (k 1024..2047)
  const float* bihp = role ? b_ih1 : b_ih0;
  const float* bhhp = role ? b_hh1 : b_hh0;

  const int lane = tid & 63, wid = tid >> 6;

  // ---- load weight slice into LDS: 48 rows (src x gate x col) of 1024 f32
  // LDS B layout: [kbg=src*64+k16][col_t=gate*8+c] : 32B of 16 f16, col stride 40B
#pragma unroll
  for (int j = 0; j < 6; ++j) {
    const int rid = wid * 6 + j;
    const int wsrc = rid / 24;
    const int rem = rid % 24;
    const int gate = rem >> 3, c = rem & 7;
    const float* wrow = (wsrc ? wsrc1 : wsrc0) + (size_t)(gate * 1024 + cbase + c) * 1024 + lane * 16;
    f16 v[16];
#pragma unroll
    for (int q = 0; q < 4; ++q) {
      const float4 f = ((const float4*)wrow)[q];
      v[q * 4 + 0] = (f16)f.x; v[q * 4 + 1] = (f16)f.y;
      v[q * 4 + 2] = (f16)f.z; v[q * 4 + 3] = (f16)f.w;
    }
    const int kbg = wsrc * 64 + lane;
    const int ct = gate * 8 + c;
    unsigned char* p = smem + kbg * 960 + ct * 40;
    const f16x4* vv = (const f16x4*)v;
    *(f16x4*)(p) = vv[0];
    *(f16x4*)(p + 8) = vv[1];
    *(f16x4*)(p + 16) = vv[2];
    *(f16x4*)(p + 24) = vv[3];
  }

  // ---- finish-phase per-thread constants: thread -> (batch fb, col fc)
  const int fb = tid >> 3, fc = tid & 7;
  const int cg = cbase + fc;
  const float bihr = bihp[cg], bihz = bihp[1024 + cg], bihn = bihp[2048 + cg];
  const float bhhr = bhhp[cg], bhhz = bhhp[1024 + cg], bhhn = bhhp[2048 + cg];
  float hprev = hidden[(size_t)role * 65536 + fb * 1024 + cg];

  // ---- MFMA wave roles
  const int src = wid & 1;          // 0: recurrent A, 1: input A
  const int mt = (wid >> 1) & 1;    // batch-row half (32 rows)
  const int kh = wid >> 2;          // K half within source (512)
  const int rowB = mt * 32 + (lane & 31);
  const int kg = lane >> 5;
  const int colf = lane & 31;
  const int colm = (colf < 24) ? colf : (colf - 8);
  const unsigned bofs_base = (unsigned)(src * 64 + kh * 32) * 960 + colm * 40 + kg * 16;
  float* Cpl = (float*)(smem + C_OFF);

  __syncthreads();

  unsigned step_target = 256u;
  for (int s = 0; s <= 512; ++s) {
    const bool active = role ? (s >= 1) : (s < 512);
    f32x16 acc;
#pragma unroll
    for (int e = 0; e < 16; ++e) acc[e] = 0.0f;

    if (active) {
      const f16* Abase;
      bool isring;
      if (role == 0) {
        isring = (src == 0);
        Abase = src ? (xslab + (size_t)s * 65536) : (h0ring + (unsigned)((s - 1) & 1) * 65536);
      } else {
        isring = true;
        Abase = src ? (h0ring + (unsigned)((s - 1) & 1) * 65536) : (h1ring + (unsigned)(s & 1) * 65536);
      }
      const f16* ap = Abase + (kh * 32) * 1024 + rowB * 16 + kg * 8;
      unsigned bofs = bofs_base;
      if (isring) GEMM_BODY(LD_NT); else GEMM_BODY(LD_CA);

      if (kh == 1) {
        float* pf = (float*)(smem + PART_OFF + (src * 2 + mt) * 5120 + lane * 80);
#pragma unroll
        for (int e = 0; e < 16; ++e) pf[e] = acc[e];
      }
    }
    __syncthreads();
    if (active && kh == 0) {
      const float* pf = (const float*)(smem + PART_OFF + (src * 2 + mt) * 5120 + lane * 80);
#pragma unroll
      for (int e = 0; e < 16; ++e) acc[e] += pf[e];
      if (colf < 24) {
#pragma unroll
        for (int r = 0; r < 16; ++r) {
          const int row = (r & 3) + 8 * (r >> 2) + 4 * kg + mt * 32;
          Cpl[src * 1664 + row * 26 + colf] = acc[r];
        }
      }
    }
    __syncthreads();
    float hnew = 0.0f;
    if (active) {
      const float hr = Cpl[fb * 26 + fc],      xr = Cpl[1664 + fb * 26 + fc];
      const float hz = Cpl[fb * 26 + 8 + fc],  xz = Cpl[1664 + fb * 26 + 8 + fc];
      const float hn = Cpl[fb * 26 + 16 + fc], xn = Cpl[1664 + fb * 26 + 16 + fc];
      const float r = 1.0f / (1.0f + exp2f(-1.4426950408889634f * (xr + bihr + hr + bhhr)));
      const float z = 1.0f / (1.0f + exp2f(-1.4426950408889634f * (xz + bihz + hz + bhhz)));
      const float pn = (xn + bihn) + r * (hn + bhhn);
      const float u = exp2f(2.8853900817779268f * pn);
      const float n = 1.0f - 2.0f / (u + 1.0f);
      hnew = (1.0f - z) * n + z * hprev;
      hprev = hnew;
      f16* ring = role ? (h1ring + (unsigned)((s - 1) & 1) * 65536)
                       : (h0ring + (unsigned)(s & 1) * 65536);
      __builtin_nontemporal_store((f16)hnew, ring + (cg >> 4) * 1024 + fb * 16 + (cg & 15));
    }
    __syncthreads();  // compiler drains vmcnt before s_barrier -> all waves' ring stores complete
    if (tid == 0) {
      __hip_atomic_fetch_add(root, 1u, __ATOMIC_RELEASE, __HIP_MEMORY_SCOPE_AGENT);
    }
    // out[] stores overlap the barrier spin (not consumed by peers)
    if (active && role) {
      __builtin_nontemporal_store(hnew, out + ((size_t)fb * 512 + (s - 1)) * 1024 + cg);
      if (s == 512)
        __builtin_nontemporal_store(hnew, out + Y1_ELEMS + 65536u + fb * 1024u + cg);
    } else if (active && s == 511) {
      __builtin_nontemporal_store(hnew, out + Y1_ELEMS + fb * 1024u + cg);
    }
    if (tid == 0) {
      while (__hip_atomic_load(root, __ATOMIC_RELAXED, __HIP_MEMORY_SCOPE_AGENT) < step_target) {
        __builtin_amdgcn_s_sleep(1);
      }
      asm volatile("" ::: "memory");
    }
    step_target += 256u;
    __syncthreads();
  }
}

// ---------------------------------------------------------------------------
extern "C" void kernel_launch(void* const* d_in, const int* in_sizes, int n_in,
                              void* d_out, int out_size, void* d_ws, size_t ws_size,
                              hipStream_t stream) {
  (void)in_sizes; (void)n_in; (void)out_size; (void)ws_size;
  const float* x      = (const float*)d_in[0];
  const float* hidden = (const float*)d_in[1];
  const float* w_ih0  = (const float*)d_in[2];
  const float* w_hh0  = (const float*)d_in[3];
  const float* b_ih0  = (const float*)d_in[4];
  const float* b_hh0  = (const float*)d_in[5];
  const float* w_ih1  = (const float*)d_in[6];
  const float* w_hh1  = (const float*)d_in[7];
  const float* b_ih1  = (const float*)d_in[8];
  const float* b_hh1  = (const float*)d_in[9];
  float* out = (float*)d_out;

  unsigned char* ws = (unsigned char*)d_ws;
  f16* slab = (f16*)ws;                                   // 67,108,864 B
  f16* h0r = (f16*)(ws + 67108864u);                      //    262,144 B
  f16* h1r = (f16*)(ws + 67108864u + 262144u);            //    262,144 B
  unsigned* root = (unsigned*)(ws + 67108864u + 524288u); //        128 B

  hipLaunchKernelGGL(k_convert_x, dim3(512, 16), dim3(512), 0, stream, x, slab);
  hipLaunchKernelGGL(k_init, dim3(512), dim3(256), 0, stream, hidden, h0r, h1r, root);
  hipLaunchKernelGGL(k_gru, dim3(256), dim3(512), 0, stream,
                     w_ih0, w_hh0, b_ih0, b_hh0, w_ih1, w_hh1, b_ih1, b_hh1,
                     hidden, slab, h0r, h1r, root, out);
}

// Round 5
// 7953.741 us; speedup vs baseline: 1.2655x; 1.2150x over previous
//
#include <hip/hip_runtime.h>

typedef _Float16 f16;
typedef f16 f16x4 __attribute__((ext_vector_type(4)));
typedef f16 f16x8 __attribute__((ext_vector_type(8)));
typedef float f32x16 __attribute__((ext_vector_type(16)));

#define LDS_BYTES 156672
#define PART_OFF  122880
#define C_OFF     143360
#define Y1_ELEMS  33554432u

// ctrs layout (unsigned words; 128B-strided lines)
#define ACNT_OFF  0    // +class*32 : per-class arrival counters (RELEASE adds)
#define ROOT_OFF  256  // root counter (8 relaxed adds/step)
#define LGEN_OFF  288  // +class*32 : per-class generation lines (1 add, 31 pollers)
#define CTR_WORDS 832

// ---------------------------------------------------------------------------
// x[b][t][k] (f32) -> slab[t][k/16][b][k%16] (f16)   (MFMA A-fragment layout)
// ---------------------------------------------------------------------------
__global__ void k_convert_x(const float* __restrict__ x, f16* __restrict__ slab) {
  __shared__ float tile[64][65];
  const int t = blockIdx.x;
  const int kc = blockIdx.y;
  {
    const int row = threadIdx.x >> 3, c8 = threadIdx.x & 7;
    const float* src = x + (((size_t)row << 9) + t) * 1024 + kc * 64 + c8 * 8;
    const float4 v0 = ((const float4*)src)[0];
    const float4 v1 = ((const float4*)src)[1];
    float* d = &tile[row][c8 * 8];
    d[0] = v0.x; d[1] = v0.y; d[2] = v0.z; d[3] = v0.w;
    d[4] = v1.x; d[5] = v1.y; d[6] = v1.z; d[7] = v1.w;
  }
  __syncthreads();
  {
    const int kbl = threadIdx.x >> 7;
    const int b = (threadIdx.x >> 1) & 63;
    const int half = threadIdx.x & 1;
    const float* s = &tile[b][kbl * 16 + half * 8];
    f16x8 o;
#pragma unroll
    for (int j = 0; j < 8; ++j) o[j] = (f16)s[j];
    f16* dst = slab + (size_t)t * 65536 + (size_t)(kc * 4 + kbl) * 1024 + b * 16 + half * 8;
    *(f16x8*)dst = o;
  }
}

// ---------------------------------------------------------------------------
// hidden[2][64][1024] f32 -> ring slot 1 of each layer (fragment layout).
// Also zero the barrier counter block.
// ---------------------------------------------------------------------------
__global__ void k_init(const float* __restrict__ hidden, f16* __restrict__ h0r,
                       f16* __restrict__ h1r, unsigned* __restrict__ ctrs) {
  const int idx = blockIdx.x * 256 + threadIdx.x;
  const int layer = idx >> 16, rem = idx & 65535, b = rem >> 10, k = rem & 1023;
  const float v = hidden[idx];
  f16* ring = layer ? h1r : h0r;
  ring[65536 + (k >> 4) * 1024 + b * 16 + (k & 15)] = (f16)v;
  if (idx < CTR_WORDS) ctrs[idx] = 0u;
}

// A-fragment loads: nontemporal (rings) vs cached (x slab).
#define LD_NT(p) __builtin_nontemporal_load((const f16x8*)(p))
#define LD_CA(p) (*(const f16x8*)(p))

// 2-stage software-pipelined K-loop: batches of 8 f16x8 A-frags in flight.
#define GEMM_BODY(LD)                                                          \
  do {                                                                         \
    f16x8 ab0[8], ab1[8];                                                      \
    _Pragma("unroll") for (int j = 0; j < 8; ++j) ab0[j] = LD(ap + j * 1024);  \
    _Pragma("unroll") for (int j = 0; j < 8; ++j) ab1[j] = LD(ap + (8 + j) * 1024); \
    _Pragma("unroll") for (int j = 0; j < 8; ++j) {                            \
      const f16x4 blo = *(const f16x4*)(smem + bofs);                          \
      const f16x4 bhi = *(const f16x4*)(smem + bofs + 8);                      \
      const f16x8 bb = __builtin_shufflevector(blo, bhi, 0, 1, 2, 3, 4, 5, 6, 7); \
      acc = __builtin_amdgcn_mfma_f32_32x32x16_f16(ab0[j], bb, acc, 0, 0, 0);  \
      bofs += 960;                                                             \
      ab0[j] = LD(ap + (16 + j) * 1024);                                       \
    }                                                                          \
    _Pragma("unroll") for (int j = 0; j < 8; ++j) {                            \
      const f16x4 blo = *(const f16x4*)(smem + bofs);                          \
      const f16x4 bhi = *(const f16x4*)(smem + bofs + 8);                      \
      const f16x8 bb = __builtin_shufflevector(blo, bhi, 0, 1, 2, 3, 4, 5, 6, 7); \
      acc = __builtin_amdgcn_mfma_f32_32x32x16_f16(ab1[j], bb, acc, 0, 0, 0);  \
      bofs += 960;                                                             \
      ab1[j] = LD(ap + (24 + j) * 1024);                                       \
    }                                                                          \
    _Pragma("unroll") for (int j = 0; j < 8; ++j) {                            \
      const f16x4 blo = *(const f16x4*)(smem + bofs);                          \
      const f16x4 bhi = *(const f16x4*)(smem + bofs + 8);                      \
      const f16x8 bb = __builtin_shufflevector(blo, bhi, 0, 1, 2, 3, 4, 5, 6, 7); \
      acc = __builtin_amdgcn_mfma_f32_32x32x16_f16(ab0[j], bb, acc, 0, 0, 0);  \
      bofs += 960;                                                             \
    }                                                                          \
    _Pragma("unroll") for (int j = 0; j < 8; ++j) {                            \
      const f16x4 blo = *(const f16x4*)(smem + bofs);                          \
      const f16x4 bhi = *(const f16x4*)(smem + bofs + 8);                      \
      const f16x8 bb = __builtin_shufflevector(blo, bhi, 0, 1, 2, 3, 4, 5, 6, 7); \
      acc = __builtin_amdgcn_mfma_f32_32x32x16_f16(ab1[j], bb, acc, 0, 0, 0);  \
      bofs += 960;                                                             \
    }                                                                          \
  } while (0)

// ---------------------------------------------------------------------------
// Persistent 2-layer GRU. 256 wgs (128/layer, 8 h-cols each), weights in LDS.
// Barrier: EVERY wg release-adds (R2-proven publish: own-L2 wbl2 before add)
// to its class arrival line (8 lines x 32 RMWs). Leaders (bid<8) relax-add
// root, poll root, bump class generation line; classmates poll only that.
// No line is both RMW-hammered and mass-polled. No XCC_ID dependence.
// ---------------------------------------------------------------------------
__launch_bounds__(512, 1)
__global__ void k_gru(const float* __restrict__ w_ih0, const float* __restrict__ w_hh0,
                      const float* __restrict__ b_ih0, const float* __restrict__ b_hh0,
                      const float* __restrict__ w_ih1, const float* __restrict__ w_hh1,
                      const float* __restrict__ b_ih1, const float* __restrict__ b_hh1,
                      const float* __restrict__ hidden, const f16* __restrict__ xslab,
                      f16* __restrict__ h0ring, f16* __restrict__ h1ring,
                      unsigned* __restrict__ ctrs, float* __restrict__ out) {
  __shared__ __align__(16) unsigned char smem[LDS_BYTES];
  const int tid = threadIdx.x;
  const int bid = blockIdx.x;
  const int role = (bid >> 3) & 1;                 // perf heuristic only
  const int chunk = ((bid >> 4) << 3) | (bid & 7); // 0..127
  const int cbase = chunk * 8;

  const float* wsrc0 = role ? w_hh1 : w_hh0;  // recurrent half (k 0..1023)
  const float* wsrc1 = role ? w_ih1 : w_ih0;  // input half     (k 1024..2047)
  const float* bihp = role ? b_ih1 : b_ih0;
  const float* bhhp = role ? b_hh1 : b_hh0;

  const int lane = tid & 63, wid = tid >> 6;

  // ---- load weight slice into LDS: 48 rows (src x gate x col) of 1024 f32
  // LDS B layout: [kbg=src*64+k16][col_t=gate*8+c] : 32B of 16 f16, col stride 40B
#pragma unroll
  for (int j = 0; j < 6; ++j) {
    const int rid = wid * 6 + j;
    const int wsrc = rid / 24;
    const int rem = rid % 24;
    const int gate = rem >> 3, c = rem & 7;
    const float* wrow = (wsrc ? wsrc1 : wsrc0) + (size_t)(gate * 1024 + cbase + c) * 1024 + lane * 16;
    f16 v[16];
#pragma unroll
    for (int q = 0; q < 4; ++q) {
      const float4 f = ((const float4*)wrow)[q];
      v[q * 4 + 0] = (f16)f.x; v[q * 4 + 1] = (f16)f.y;
      v[q * 4 + 2] = (f16)f.z; v[q * 4 + 3] = (f16)f.w;
    }
    const int kbg = wsrc * 64 + lane;
    const int ct = gate * 8 + c;
    unsigned char* p = smem + kbg * 960 + ct * 40;
    const f16x4* vv = (const f16x4*)v;
    *(f16x4*)(p) = vv[0];
    *(f16x4*)(p + 8) = vv[1];
    *(f16x4*)(p + 16) = vv[2];
    *(f16x4*)(p + 24) = vv[3];
  }

  // ---- finish-phase per-thread constants: thread -> (batch fb, col fc)
  const int fb = tid >> 3, fc = tid & 7;
  const int cg = cbase + fc;
  const float bihr = bihp[cg], bihz = bihp[1024 + cg], bihn = bihp[2048 + cg];
  const float bhhr = bhhp[cg], bhhz = bhhp[1024 + cg], bhhn = bhhp[2048 + cg];
  float hprev = hidden[(size_t)role * 65536 + fb * 1024 + cg];

  // ---- barrier line pointers (128B-strided lines)
  unsigned* const acnt = ctrs + ACNT_OFF + (bid & 7) * 32;  // class arrival line
  unsigned* const rootp = ctrs + ROOT_OFF;                  // root counter
  unsigned* const lgenx = ctrs + LGEN_OFF + (bid & 7) * 32; // class generation line
  const bool leader = (bid < 8);

  // ---- MFMA wave roles
  const int src = wid & 1;          // 0: recurrent A, 1: input A
  const int mt = (wid >> 1) & 1;    // batch-row half (32 rows)
  const int kh = wid >> 2;          // K half within source (512)
  const int rowB = mt * 32 + (lane & 31);
  const int kg = lane >> 5;
  const int colf = lane & 31;
  const int colm = (colf < 24) ? colf : (colf - 8);
  const unsigned bofs_base = (unsigned)(src * 64 + kh * 32) * 960 + colm * 40 + kg * 16;
  float* Cpl = (float*)(smem + C_OFF);

  __syncthreads();

  for (int s = 0; s <= 512; ++s) {
    const bool active = role ? (s >= 1) : (s < 512);
    f32x16 acc;
#pragma unroll
    for (int e = 0; e < 16; ++e) acc[e] = 0.0f;

    if (active) {
      const f16* Abase;
      bool isring;
      if (role == 0) {
        isring = (src == 0);
        Abase = src ? (xslab + (size_t)s * 65536) : (h0ring + (unsigned)((s - 1) & 1) * 65536);
      } else {
        isring = true;
        Abase = src ? (h0ring + (unsigned)((s - 1) & 1) * 65536) : (h1ring + (unsigned)(s & 1) * 65536);
      }
      const f16* ap = Abase + (kh * 32) * 1024 + rowB * 16 + kg * 8;
      unsigned bofs = bofs_base;
      if (isring) GEMM_BODY(LD_NT); else GEMM_BODY(LD_CA);

      if (kh == 1) {
        float* pf = (float*)(smem + PART_OFF + (src * 2 + mt) * 5120 + lane * 80);
#pragma unroll
        for (int e = 0; e < 16; ++e) pf[e] = acc[e];
      }
    }
    __syncthreads();
    if (active && kh == 0) {
      const float* pf = (const float*)(smem + PART_OFF + (src * 2 + mt) * 5120 + lane * 80);
#pragma unroll
      for (int e = 0; e < 16; ++e) acc[e] += pf[e];
      if (colf < 24) {
#pragma unroll
        for (int r = 0; r < 16; ++r) {
          const int row = (r & 3) + 8 * (r >> 2) + 4 * kg + mt * 32;
          Cpl[src * 1664 + row * 26 + colf] = acc[r];
        }
      }
    }
    __syncthreads();
    float hnew = 0.0f;
    if (active) {
      const float hr = Cpl[fb * 26 + fc],      xr = Cpl[1664 + fb * 26 + fc];
      const float hz = Cpl[fb * 26 + 8 + fc],  xz = Cpl[1664 + fb * 26 + 8 + fc];
      const float hn = Cpl[fb * 26 + 16 + fc], xn = Cpl[1664 + fb * 26 + 16 + fc];
      const float r = 1.0f / (1.0f + exp2f(-1.4426950408889634f * (xr + bihr + hr + bhhr)));
      const float z = 1.0f / (1.0f + exp2f(-1.4426950408889634f * (xz + bihz + hz + bhhz)));
      const float pn = (xn + bihn) + r * (hn + bhhn);
      const float u = exp2f(2.8853900817779268f * pn);
      const float n = 1.0f - 2.0f / (u + 1.0f);
      hnew = (1.0f - z) * n + z * hprev;
      hprev = hnew;
      f16* ring = role ? (h1ring + (unsigned)((s - 1) & 1) * 65536)
                       : (h0ring + (unsigned)(s & 1) * 65536);
      __builtin_nontemporal_store((f16)hnew, ring + (cg >> 4) * 1024 + fb * 16 + (cg & 15));
    }
    __syncthreads();  // vmcnt drained -> this wg's ring stores resident in local L2
    const unsigned sp1 = (unsigned)s + 1u;
    if (tid == 0) {
      // RELEASE: wbl2 flushes THIS wg's own L2 (R2-proven publish), then add.
      __hip_atomic_fetch_add(acnt, 1u, __ATOMIC_RELEASE, __HIP_MEMORY_SCOPE_AGENT);
    }
    // out[] stores overlap the barrier (not consumed by peers)
    if (active && role) {
      __builtin_nontemporal_store(hnew, out + ((size_t)fb * 512 + (s - 1)) * 1024 + cg);
      if (s == 512)
        __builtin_nontemporal_store(hnew, out + Y1_ELEMS + 65536u + fb * 1024u + cg);
    } else if (active && s == 511) {
      __builtin_nontemporal_store(hnew, out + Y1_ELEMS + fb * 1024u + cg);
    }
    if (tid == 0) {
      if (leader) {
        while (__hip_atomic_load(acnt, __ATOMIC_RELAXED, __HIP_MEMORY_SCOPE_AGENT) < 32u * sp1)
          __builtin_amdgcn_s_sleep(1);
        __hip_atomic_fetch_add(rootp, 1u, __ATOMIC_RELAXED, __HIP_MEMORY_SCOPE_AGENT);
        while (__hip_atomic_load(rootp, __ATOMIC_RELAXED, __HIP_MEMORY_SCOPE_AGENT) < 8u * sp1)
          __builtin_amdgcn_s_sleep(1);
        __hip_atomic_fetch_add(lgenx, 1u, __ATOMIC_RELAXED, __HIP_MEMORY_SCOPE_AGENT);
      } else {
        while (__hip_atomic_load(lgenx, __ATOMIC_RELAXED, __HIP_MEMORY_SCOPE_AGENT) < sp1)
          __builtin_amdgcn_s_sleep(1);
      }
      asm volatile("" ::: "memory");
    }
    __syncthreads();
  }
}

// ---------------------------------------------------------------------------
extern "C" void kernel_launch(void* const* d_in, const int* in_sizes, int n_in,
                              void* d_out, int out_size, void* d_ws, size_t ws_size,
                              hipStream_t stream) {
  (void)in_sizes; (void)n_in; (void)out_size; (void)ws_size;
  const float* x      = (const float*)d_in[0];
  const float* hidden = (const float*)d_in[1];
  const float* w_ih0  = (const float*)d_in[2];
  const float* w_hh0  = (const float*)d_in[3];
  const float* b_ih0  = (const float*)d_in[4];
  const float* b_hh0  = (const float*)d_in[5];
  const float* w_ih1  = (const float*)d_in[6];
  const float* w_hh1  = (const float*)d_in[7];
  const float* b_ih1  = (const float*)d_in[8];
  const float* b_hh1  = (const float*)d_in[9];
  float* out = (float*)d_out;

  unsigned char* ws = (unsigned char*)d_ws;
  f16* slab = (f16*)ws;                                    // 67,108,864 B
  f16* h0r = (f16*)(ws + 67108864u);                       //    262,144 B
  f16* h1r = (f16*)(ws + 67108864u + 262144u);             //    262,144 B
  unsigned* ctrs = (unsigned*)(ws + 67108864u + 524288u);  //      3,328 B
  hipLaunchKernelGGL(k_convert_x, dim3(512, 16), dim3(512), 0, stream, x, slab);
  hipLaunchKernelGGL(k_init, dim3(512), dim3(256), 0, stream, hidden, h0r, h1r, ctrs);
  hipLaunchKernelGGL(k_gru, dim3(256), dim3(512), 0, stream,
                     w_ih0, w_hh0, b_ih0, b_hh0, w_ih1, w_hh1, b_ih1, b_hh1,
                     hidden, slab, h0r, h1r, ctrs, out);
}

// Round 6
// 4715.363 us; speedup vs baseline: 2.1347x; 1.6868x over previous
//
#include <hip/hip_runtime.h>

typedef _Float16 f16;
typedef f16 f16x4 __attribute__((ext_vector_type(4)));
typedef f16 f16x8 __attribute__((ext_vector_type(8)));
typedef float f32x16 __attribute__((ext_vector_type(16)));

#define LDS_BYTES 156672
#define PART_OFF  122880
#define C_OFF     143360
#define Y1_ELEMS  33554432u

// ctrs layout (unsigned words; 128B-strided lines)
#define ACNT_OFF  0    // +class*32 : per-class arrival counters (relaxed adds)
#define ROOT_OFF  256  // root counter (8 relaxed adds/step)
#define LGEN_OFF  288  // +class*32 : per-class generation lines (1 add, 31 pollers)
#define CTR_WORDS 832

// ---------------------------------------------------------------------------
// x[b][t][k] (f32) -> slab[t][k/16][b][k%16] (f16)   (MFMA A-fragment layout)
// ---------------------------------------------------------------------------
__global__ void k_convert_x(const float* __restrict__ x, f16* __restrict__ slab) {
  __shared__ float tile[64][65];
  const int t = blockIdx.x;
  const int kc = blockIdx.y;
  {
    const int row = threadIdx.x >> 3, c8 = threadIdx.x & 7;
    const float* src = x + (((size_t)row << 9) + t) * 1024 + kc * 64 + c8 * 8;
    const float4 v0 = ((const float4*)src)[0];
    const float4 v1 = ((const float4*)src)[1];
    float* d = &tile[row][c8 * 8];
    d[0] = v0.x; d[1] = v0.y; d[2] = v0.z; d[3] = v0.w;
    d[4] = v1.x; d[5] = v1.y; d[6] = v1.z; d[7] = v1.w;
  }
  __syncthreads();
  {
    const int kbl = threadIdx.x >> 7;
    const int b = (threadIdx.x >> 1) & 63;
    const int half = threadIdx.x & 1;
    const float* s = &tile[b][kbl * 16 + half * 8];
    f16x8 o;
#pragma unroll
    for (int j = 0; j < 8; ++j) o[j] = (f16)s[j];
    f16* dst = slab + (size_t)t * 65536 + (size_t)(kc * 4 + kbl) * 1024 + b * 16 + half * 8;
    *(f16x8*)dst = o;
  }
}

// ---------------------------------------------------------------------------
// hidden[2][64][1024] f32 -> ring slot 1 of each layer (fragment layout).
// Also zero the barrier counter block.
// ---------------------------------------------------------------------------
__global__ void k_init(const float* __restrict__ hidden, f16* __restrict__ h0r,
                       f16* __restrict__ h1r, unsigned* __restrict__ ctrs) {
  const int idx = blockIdx.x * 256 + threadIdx.x;
  const int layer = idx >> 16, rem = idx & 65535, b = rem >> 10, k = rem & 1023;
  const float v = hidden[idx];
  f16* ring = layer ? h1r : h0r;
  ring[65536 + (k >> 4) * 1024 + b * 16 + (k & 15)] = (f16)v;
  if (idx < CTR_WORDS) ctrs[idx] = 0u;
}

// A-fragment loads: nontemporal (rings) vs cached (x slab).
#define LD_NT(p) __builtin_nontemporal_load((const f16x8*)(p))
#define LD_CA(p) (*(const f16x8*)(p))

// 2-stage software-pipelined K-loop: batches of 8 f16x8 A-frags in flight.
#define GEMM_BODY(LD)                                                          \
  do {                                                                         \
    f16x8 ab0[8], ab1[8];                                                      \
    _Pragma("unroll") for (int j = 0; j < 8; ++j) ab0[j] = LD(ap + j * 1024);  \
    _Pragma("unroll") for (int j = 0; j < 8; ++j) ab1[j] = LD(ap + (8 + j) * 1024); \
    _Pragma("unroll") for (int j = 0; j < 8; ++j) {                            \
      const f16x4 blo = *(const f16x4*)(smem + bofs);                          \
      const f16x4 bhi = *(const f16x4*)(smem + bofs + 8);                      \
      const f16x8 bb = __builtin_shufflevector(blo, bhi, 0, 1, 2, 3, 4, 5, 6, 7); \
      acc = __builtin_amdgcn_mfma_f32_32x32x16_f16(ab0[j], bb, acc, 0, 0, 0);  \
      bofs += 960;                                                             \
      ab0[j] = LD(ap + (16 + j) * 1024);                                       \
    }                                                                          \
    _Pragma("unroll") for (int j = 0; j < 8; ++j) {                            \
      const f16x4 blo = *(const f16x4*)(smem + bofs);                          \
      const f16x4 bhi = *(const f16x4*)(smem + bofs + 8);                      \
      const f16x8 bb = __builtin_shufflevector(blo, bhi, 0, 1, 2, 3, 4, 5, 6, 7); \
      acc = __builtin_amdgcn_mfma_f32_32x32x16_f16(ab1[j], bb, acc, 0, 0, 0);  \
      bofs += 960;                                                             \
      ab1[j] = LD(ap + (24 + j) * 1024);                                       \
    }                                                                          \
    _Pragma("unroll") for (int j = 0; j < 8; ++j) {                            \
      const f16x4 blo = *(const f16x4*)(smem + bofs);                          \
      const f16x4 bhi = *(const f16x4*)(smem + bofs + 8);                      \
      const f16x8 bb = __builtin_shufflevector(blo, bhi, 0, 1, 2, 3, 4, 5, 6, 7); \
      acc = __builtin_amdgcn_mfma_f32_32x32x16_f16(ab0[j], bb, acc, 0, 0, 0);  \
      bofs += 960;                                                             \
    }                                                                          \
    _Pragma("unroll") for (int j = 0; j < 8; ++j) {                            \
      const f16x4 blo = *(const f16x4*)(smem + bofs);                          \
      const f16x4 bhi = *(const f16x4*)(smem + bofs + 8);                      \
      const f16x8 bb = __builtin_shufflevector(blo, bhi, 0, 1, 2, 3, 4, 5, 6, 7); \
      acc = __builtin_amdgcn_mfma_f32_32x32x16_f16(ab1[j], bb, acc, 0, 0, 0);  \
      bofs += 960;                                                             \
    }                                                                          \
  } while (0)

// ---------------------------------------------------------------------------
// Persistent 2-layer GRU. 256 wgs (128/layer, 8 h-cols each), weights in LDS.
// Publish: ring stores are AGENT-scope relaxed atomic stores (paired 32-bit)
// -> global_store_dword sc1: write-through to the coherence point. No wbl2,
// no release, no invalidates anywhere in the step loop. Barrier is the R5
// hierarchy (class arrival lines -> root -> class generation lines), all
// RELAXED; __syncthreads' vmcnt(0) drain orders ring stores before arrival.
// ---------------------------------------------------------------------------
__launch_bounds__(512, 1)
__global__ void k_gru(const float* __restrict__ w_ih0, const float* __restrict__ w_hh0,
                      const float* __restrict__ b_ih0, const float* __restrict__ b_hh0,
                      const float* __restrict__ w_ih1, const float* __restrict__ w_hh1,
                      const float* __restrict__ b_ih1, const float* __restrict__ b_hh1,
                      const float* __restrict__ hidden, const f16* __restrict__ xslab,
                      f16* __restrict__ h0ring, f16* __restrict__ h1ring,
                      unsigned* __restrict__ ctrs, float* __restrict__ out) {
  __shared__ __align__(16) unsigned char smem[LDS_BYTES];
  const int tid = threadIdx.x;
  const int bid = blockIdx.x;
  const int role = (bid >> 3) & 1;                 // perf heuristic only
  const int chunk = ((bid >> 4) << 3) | (bid & 7); // 0..127
  const int cbase = chunk * 8;

  const float* wsrc0 = role ? w_hh1 : w_hh0;  // recurrent half (k 0..1023)
  const float* wsrc1 = role ? w_ih1 : w_ih0;  // input half     (k 1024..2047)
  const float* bihp = role ? b_ih1 : b_ih0;
  const float* bhhp = role ? b_hh1 : b_hh0;

  const int lane = tid & 63, wid = tid >> 6;

  // ---- load weight slice into LDS: 48 rows (src x gate x col) of 1024 f32
  // LDS B layout: [kbg=src*64+k16][col_t=gate*8+c] : 32B of 16 f16, col stride 40B
#pragma unroll
  for (int j = 0; j < 6; ++j) {
    const int rid = wid * 6 + j;
    const int wsrc = rid / 24;
    const int rem = rid % 24;
    const int gate = rem >> 3, c = rem & 7;
    const float* wrow = (wsrc ? wsrc1 : wsrc0) + (size_t)(gate * 1024 + cbase + c) * 1024 + lane * 16;
    f16 v[16];
#pragma unroll
    for (int q = 0; q < 4; ++q) {
      const float4 f = ((const float4*)wrow)[q];
      v[q * 4 + 0] = (f16)f.x; v[q * 4 + 1] = (f16)f.y;
      v[q * 4 + 2] = (f16)f.z; v[q * 4 + 3] = (f16)f.w;
    }
    const int kbg = wsrc * 64 + lane;
    const int ct = gate * 8 + c;
    unsigned char* p = smem + kbg * 960 + ct * 40;
    const f16x4* vv = (const f16x4*)v;
    *(f16x4*)(p) = vv[0];
    *(f16x4*)(p + 8) = vv[1];
    *(f16x4*)(p + 16) = vv[2];
    *(f16x4*)(p + 24) = vv[3];
  }

  // ---- finish-phase per-thread constants: thread -> (batch fb, col fc)
  const int fb = tid >> 3, fc = tid & 7;
  const int cg = cbase + fc;
  const float bihr = bihp[cg], bihz = bihp[1024 + cg], bihn = bihp[2048 + cg];
  const float bhhr = bhhp[cg], bhhz = bhhp[1024 + cg], bhhn = bhhp[2048 + cg];
  float hprev = hidden[(size_t)role * 65536 + fb * 1024 + cg];

  // ---- barrier line pointers (128B-strided lines)
  unsigned* const acnt = ctrs + ACNT_OFF + (bid & 7) * 32;  // class arrival line
  unsigned* const rootp = ctrs + ROOT_OFF;                  // root counter
  unsigned* const lgenx = ctrs + LGEN_OFF + (bid & 7) * 32; // class generation line
  const bool leader = (bid < 8);

  // ---- MFMA wave roles
  const int src = wid & 1;          // 0: recurrent A, 1: input A
  const int mt = (wid >> 1) & 1;    // batch-row half (32 rows)
  const int kh = wid >> 2;          // K half within source (512)
  const int rowB = mt * 32 + (lane & 31);
  const int kg = lane >> 5;
  const int colf = lane & 31;
  const int colm = (colf < 24) ? colf : (colf - 8);
  const unsigned bofs_base = (unsigned)(src * 64 + kh * 32) * 960 + colm * 40 + kg * 16;
  float* Cpl = (float*)(smem + C_OFF);

  __syncthreads();

  for (int s = 0; s <= 512; ++s) {
    const bool active = role ? (s >= 1) : (s < 512);
    f32x16 acc;
#pragma unroll
    for (int e = 0; e < 16; ++e) acc[e] = 0.0f;

    if (active) {
      const f16* Abase;
      bool isring;
      if (role == 0) {
        isring = (src == 0);
        Abase = src ? (xslab + (size_t)s * 65536) : (h0ring + (unsigned)((s - 1) & 1) * 65536);
      } else {
        isring = true;
        Abase = src ? (h0ring + (unsigned)((s - 1) & 1) * 65536) : (h1ring + (unsigned)(s & 1) * 65536);
      }
      const f16* ap = Abase + (kh * 32) * 1024 + rowB * 16 + kg * 8;
      unsigned bofs = bofs_base;
      if (isring) GEMM_BODY(LD_NT); else GEMM_BODY(LD_CA);

      if (kh == 1) {
        float* pf = (float*)(smem + PART_OFF + (src * 2 + mt) * 5120 + lane * 80);
#pragma unroll
        for (int e = 0; e < 16; ++e) pf[e] = acc[e];
      }
    }
    __syncthreads();
    if (active && kh == 0) {
      const float* pf = (const float*)(smem + PART_OFF + (src * 2 + mt) * 5120 + lane * 80);
#pragma unroll
      for (int e = 0; e < 16; ++e) acc[e] += pf[e];
      if (colf < 24) {
#pragma unroll
        for (int r = 0; r < 16; ++r) {
          const int row = (r & 3) + 8 * (r >> 2) + 4 * kg + mt * 32;
          Cpl[src * 1664 + row * 26 + colf] = acc[r];
        }
      }
    }
    __syncthreads();
    float hnew = 0.0f;
    if (active) {
      const float hr = Cpl[fb * 26 + fc],      xr = Cpl[1664 + fb * 26 + fc];
      const float hz = Cpl[fb * 26 + 8 + fc],  xz = Cpl[1664 + fb * 26 + 8 + fc];
      const float hn = Cpl[fb * 26 + 16 + fc], xn = Cpl[1664 + fb * 26 + 16 + fc];
      const float r = 1.0f / (1.0f + exp2f(-1.4426950408889634f * (xr + bihr + hr + bhhr)));
      const float z = 1.0f / (1.0f + exp2f(-1.4426950408889634f * (xz + bihz + hz + bhhz)));
      const float pn = (xn + bihn) + r * (hn + bhhn);
      const float u = exp2f(2.8853900817779268f * pn);
      const float n = 1.0f - 2.0f / (u + 1.0f);
      hnew = (1.0f - z) * n + z * hprev;
      hprev = hnew;
      f16* ring = role ? (h1ring + (unsigned)((s - 1) & 1) * 65536)
                       : (h0ring + (unsigned)(s & 1) * 65536);
      // Pair adjacent f16s (lanes tid,tid+1) into one 32-bit AGENT-scope
      // relaxed atomic store -> global_store_dword sc1 (write-through to the
      // coherence point; no wbl2 needed to publish).
      const unsigned short myu = __builtin_bit_cast(unsigned short, (f16)hnew);
      const unsigned hiu = (unsigned)__shfl_down((int)myu, 1, 64);
      if ((fc & 1) == 0) {
        const unsigned word = (unsigned)(unsigned short)myu | (hiu << 16);
        __hip_atomic_store((unsigned*)(ring + (cg >> 4) * 1024 + fb * 16 + (cg & 15)),
                           word, __ATOMIC_RELAXED, __HIP_MEMORY_SCOPE_AGENT);
      }
    }
    __syncthreads();  // vmcnt(0) drain: ring write-throughs ACKed at coherence point
    const unsigned sp1 = (unsigned)s + 1u;
    if (tid == 0) {
      __hip_atomic_fetch_add(acnt, 1u, __ATOMIC_RELAXED, __HIP_MEMORY_SCOPE_AGENT);
    }
    // out[] stores overlap the barrier (not consumed by peers)
    if (active && role) {
      __builtin_nontemporal_store(hnew, out + ((size_t)fb * 512 + (s - 1)) * 1024 + cg);
      if (s == 512)
        __builtin_nontemporal_store(hnew, out + Y1_ELEMS + 65536u + fb * 1024u + cg);
    } else if (active && s == 511) {
      __builtin_nontemporal_store(hnew, out + Y1_ELEMS + fb * 1024u + cg);
    }
    if (tid == 0) {
      if (leader) {
        while (__hip_atomic_load(acnt, __ATOMIC_RELAXED, __HIP_MEMORY_SCOPE_AGENT) < 32u * sp1)
          __builtin_amdgcn_s_sleep(1);
        __hip_atomic_fetch_add(rootp, 1u, __ATOMIC_RELAXED, __HIP_MEMORY_SCOPE_AGENT);
        while (__hip_atomic_load(rootp, __ATOMIC_RELAXED, __HIP_MEMORY_SCOPE_AGENT) < 8u * sp1)
          __builtin_amdgcn_s_sleep(1);
        __hip_atomic_fetch_add(lgenx, 1u, __ATOMIC_RELAXED, __HIP_MEMORY_SCOPE_AGENT);
      } else {
        while (__hip_atomic_load(lgenx, __ATOMIC_RELAXED, __HIP_MEMORY_SCOPE_AGENT) < sp1)
          __builtin_amdgcn_s_sleep(1);
      }
      asm volatile("" ::: "memory");
    }
    __syncthreads();
  }
}

// ---------------------------------------------------------------------------
extern "C" void kernel_launch(void* const* d_in, const int* in_sizes, int n_in,
                              void* d_out, int out_size, void* d_ws, size_t ws_size,
                              hipStream_t stream) {
  (void)in_sizes; (void)n_in; (void)out_size; (void)ws_size;
  const float* x      = (const float*)d_in[0];
  const float* hidden = (const float*)d_in[1];
  const float* w_ih0  = (const float*)d_in[2];
  const float* w_hh0  = (const float*)d_in[3];
  const float* b_ih0  = (const float*)d_in[4];
  const float* b_hh0  = (const float*)d_in[5];
  const float* w_ih1  = (const float*)d_in[6];
  const float* w_hh1  = (const float*)d_in[7];
  const float* b_ih1  = (const float*)d_in[8];
  const float* b_hh1  = (const float*)d_in[9];
  float* out = (float*)d_out;

  unsigned char* ws = (unsigned char*)d_ws;
  f16* slab = (f16*)ws;                                    // 67,108,864 B
  f16* h0r = (f16*)(ws + 67108864u);                       //    262,144 B
  f16* h1r = (f16*)(ws + 67108864u + 262144u);             //    262,144 B
  unsigned* ctrs = (unsigned*)(ws + 67108864u + 524288u);  //      3,328 B
  hipLaunchKernelGGL(k_convert_x, dim3(512, 16), dim3(512), 0, stream, x, slab);
  hipLaunchKernelGGL(k_init, dim3(512), dim3(256), 0, stream, hidden, h0r, h1r, ctrs);
  hipLaunchKernelGGL(k_gru, dim3(256), dim3(512), 0, stream,
                     w_ih0, w_hh0, b_ih0, b_hh0, w_ih1, w_hh1, b_ih1, b_hh1,
                     hidden, slab, h0r, h1r, ctrs, out);
}